// Round 8
// baseline (1328.799 us; speedup 1.0000x reference)
//
#include <hip/hip_runtime.h>

// FSAS slab pipeline, 4 slabs of 64 rows, bf16 intermediates:
//   k2: affine(kv) + 1x1 conv 64->384 -> hid bf16 slab (66 rows incl. halo)
//       v5: LDS-staged xp (affine applied once), x read ONCE per slab.
//       Block = (row, 64-px quarter, b); wave w computes 96 out-ch (3x acc[32]).
//   k3: grouped 3x3 -> qkv bf16 slab, PATCHIFIED [ch][patch(256)][64]
//       v2: 32-row x 64-col tiles (2x per-thread work, half the halo overhead)
//   kC: per-patch circular conv (q,k in VGPRs) + LN + *v + proj 128->64 -> out
// Workspace:
//   kv  fp32 @ 0      (512)
//   whT fp32 @ 512    (24576)  whT[c*384+o] = w_hidden[o][c]
//   wpT fp32 @ 25088  (8192)   wpT[c*64+o]  = w_proj[o][c]
//   hid bf16 @ float-ofs 40960 : [4][384][66][256]  (51.9 MB)
//   qkv bf16 after hid          : [4][384][256][64]  (50.3 MB)
// Total 102,400,000 B = 97.66 MiB (< proven 99.15 MiB).

#define HW    65536
#define SLAB  64
#define HROWS 66
#define HSZ2  (HROWS*256)   // bf16 elems per (b,ch) hid plane
#define QS    16384         // bf16 elems per (b,ch) qkv plane (256 patches * 64)

__device__ __forceinline__ unsigned short f2bf(float f) {
    unsigned u = __float_as_uint(f);
    u += 0x7FFFu + ((u >> 16) & 1u);       // RNE
    return (unsigned short)(u >> 16);
}
__device__ __forceinline__ float bflo(unsigned u) { return __uint_as_float(u << 16); }
__device__ __forceinline__ float bfhi(unsigned u) { return __uint_as_float(u & 0xFFFF0000u); }

__global__ void k_prep(const float* __restrict__ prior, const float* __restrict__ wk,
                       const float* __restrict__ wh, const float* __restrict__ wp,
                       float* __restrict__ kv, float* __restrict__ whT, float* __restrict__ wpT) {
    int t = blockIdx.x * 256 + threadIdx.x;
    if (t < 512) {
        int b = t >> 7, k = t & 127;
        const float* p = prior + b * 192;
        const float* w = wk + k * 192;
        float s = 0.f;
        for (int f = 0; f < 192; ++f) s = fmaf(p[f], w[f], s);
        kv[t] = s;
        return;
    }
    t -= 512;
    if (t < 24576) {
        int c = t / 384, o = t - c * 384;
        whT[t] = wh[o * 64 + c];
        return;
    }
    t -= 24576;
    int c = t >> 6, o = t & 63;
    wpT[t] = wp[o * 128 + c];
}

// v5: block = (row, col-quarter, b). Stage xp[64ch][64px] in LDS (affine fused,
// coalesced float2), then wave w (t>>6, uniform) computes out-ch w*96..w*96+95
// in 3 iters of acc[32]. x is read exactly once per slab (no chunk re-reads).
// Weights via wave-uniform scalar loads; LDS reads conflict-free (row-contig).
__global__ __launch_bounds__(256, 4) void k2_hidden(const float* __restrict__ x,
    const float* __restrict__ whT, const float* __restrict__ kv,
    unsigned short* __restrict__ hid, int r0) {
    __shared__ float sXp[64 * 64];   // 16 KB
    int t = threadIdx.x;
    int row = blockIdx.x;            // 0..65
    int colq = blockIdx.y;           // 0..3
    int b = blockIdx.z;
    int col0 = colq * 64;
    int g = r0 - 1 + row;
    int px = t & 63;
    int wv = t >> 6;                 // 0..3, uniform per wave
    unsigned short* hb = hid + ((size_t)(b * 384 + wv * 96)) * HSZ2
                         + row * 256 + col0 + px;
    if (g < 0 || g > 255) {          // block-uniform edge path (no barrier here)
        #pragma unroll
        for (int it = 0; it < 3; ++it)
            #pragma unroll
            for (int j = 0; j < 32; ++j)
                hb[(size_t)(it * 32 + j) * HSZ2] = 0;
        return;
    }
    const float* kv1 = kv + b * 128;
    const float* kv2 = kv1 + 64;
    const float2* xb = (const float2*)(x + (size_t)b * 64 * HW + (size_t)g * 256 + col0);
    #pragma unroll
    for (int i = 0; i < 8; ++i) {    // 2048 float2 = 64ch x 32
        int idx = t + i * 256;
        int c = idx >> 5;            // 0..63
        int l2 = idx & 31;
        float2 xv = xb[(size_t)c * (HW / 2) + l2];
        float2 s;
        s.x = fmaf(xv.x, kv1[c], kv2[c]);
        s.y = fmaf(xv.y, kv1[c], kv2[c]);
        *(float2*)&sXp[c * 64 + l2 * 2] = s;
    }
    __syncthreads();
    #pragma unroll
    for (int it = 0; it < 3; ++it) {
        int obase = wv * 96 + it * 32;          // wave-uniform
        const float* wbase = whT + obase;
        float acc[32];
        #pragma unroll
        for (int j = 0; j < 32; ++j) acc[j] = 0.f;
        #pragma unroll 4
        for (int c = 0; c < 64; ++c) {
            float xv = sXp[c * 64 + px];
            const float* wr = wbase + c * 384;  // wave-uniform -> scalar loads
            #pragma unroll
            for (int j = 0; j < 32; ++j)
                acc[j] = fmaf(wr[j], xv, acc[j]);
        }
        #pragma unroll
        for (int j = 0; j < 32; ++j)
            hb[(size_t)(it * 32 + j) * HSZ2] = f2bf(acc[j]);
    }
}

// grouped 3x3 conv from bf16 hid -> bf16 qkv patchified [ch][patch][py*8+px]
// v2: 32-row x 64-col tile per block (halo 34x66), 4 pp-passes, 288 fma/thread.
__global__ __launch_bounds__(256) void k3_dw(const unsigned short* __restrict__ hid,
    const float* __restrict__ wdw, unsigned short* __restrict__ qkv) {
    __shared__ float sIn[2 * 34 * 66];
    int t = threadIdx.x;
    int bid = blockIdx.x;            // 8 tiles: tx 0..3 (x64 cols), ty 0..1 (x32 rows)
    int gl = blockIdx.y;             // 0..191
    int b = blockIdx.z;
    int tx = bid & 3, ty = bid >> 2;
    int x0 = tx * 64, y0 = ty * 32;
    const unsigned short* hbase = hid + ((size_t)(b * 384 + 2 * gl)) * HSZ2;
    for (int idx = t; idx < 2 * 34 * 66; idx += 256) {
        int chl = idx >= 2244;
        int rem = idx - chl * 2244;
        int row = rem / 66;
        int col = rem - row * 66;
        int gx = x0 + col - 1;
        float v = 0.f;
        if (gx >= 0 && gx < 256)
            v = bflo((unsigned)hbase[(size_t)chl * HSZ2 + (y0 + row) * 256 + gx]);
        sIn[idx] = v;
    }
    __syncthreads();
    int og = 2 * gl;
    float w0[18], w1[18];
    #pragma unroll
    for (int i = 0; i < 18; ++i) {
        w0[i] = wdw[(size_t)og * 18 + i];
        w1[i] = wdw[(size_t)(og + 1) * 18 + i];
    }
    unsigned short* q0 = qkv + ((size_t)(b * 384 + og)) * QS;
    #pragma unroll
    for (int pp = 0; pp < 4; ++pp) {
        int ly = pp * 8 + (t >> 5);                  // 0..31
        int lxp = (t & 31) * 2;                      // even col in tile
        float a[2][2];                               // [px][out-ch]
        #pragma unroll
        for (int px = 0; px < 2; ++px) {
            float s0 = 0.f, s1 = 0.f;
            #pragma unroll
            for (int i = 0; i < 2; ++i)
                #pragma unroll
                for (int ky = 0; ky < 3; ++ky)
                    #pragma unroll
                    for (int kx = 0; kx < 3; ++kx) {
                        float v = sIn[i * 2244 + (ly + ky) * 66 + (lxp + px + kx)];
                        s0 = fmaf(w0[i * 9 + ky * 3 + kx], v, s0);
                        s1 = fmaf(w1[i * 9 + ky * 3 + kx], v, s1);
                    }
            a[px][0] = s0; a[px][1] = s1;
        }
        int row = y0 + ly;                           // slab row 0..63
        int gx = x0 + lxp;
        int patch = (row >> 3) * 32 + (gx >> 3);     // 0..255
        int off = patch * 64 + (row & 7) * 8 + (gx & 7);   // even
        ((unsigned*)(q0 + off))[0] =
            (unsigned)f2bf(a[0][0]) | ((unsigned)f2bf(a[1][0]) << 16);
        ((unsigned*)(q0 + QS + off))[0] =
            (unsigned)f2bf(a[0][1]) | ((unsigned)f2bf(a[1][1]) << 16);
    }
}

// Fused per-patch: circular conv (q,k in regs) + LN(128) + *v + proj 128->64.
// Thread t: channel c = t&127, py-half pyh = t>>7.
// v2 dataflow: 3 barriers, no serial phase.
//   P0 conv -> sC[c][68] (float4 writes, transposed)
//   P1 reduce over c: (q4,px) mapping, 4 partials per pixel live in ONE wave,
//      combined with 2x shfl_xor -> sMu/sRstd (no sRed arrays, no t<64 phase)
//   P3 normalize from acc regs -> tvv to sT[pix][132] (aliases sC)
//   P4 proj: ds_read_b128 over channels (4/instr), weights via SGPR
__global__ __launch_bounds__(256, 2) void kC_patch(const unsigned short* __restrict__ qkv,
    const float* __restrict__ wpT, const float* __restrict__ lnw,
    const float* __restrict__ lnb, float* __restrict__ outp, int r0) {
    __shared__ __align__(16) float sBuf[128 * 68];   // P0/P1: sC[c][68]; P3/P4: sT[pix][132]
    __shared__ __align__(16) float sMu[64];
    __shared__ __align__(16) float sRstd[64];
    int t = threadIdx.x;
    int p = blockIdx.x;              // slab-local patch 0..255
    int b = blockIdx.y;
    int c = t & 127;
    int pyh = t >> 7;

    const uint4* gq = (const uint4*)(qkv + ((size_t)(b * 384 + c)) * QS + p * 64);
    const uint4* gk = (const uint4*)(qkv + ((size_t)(b * 384 + 128 + c)) * QS + p * 64);
    float q[64], k[64];
    #pragma unroll
    for (int f = 0; f < 8; ++f) {                     // 8 bf16 per uint4
        uint4 u = gq[f];
        q[f * 8 + 0] = bflo(u.x); q[f * 8 + 1] = bfhi(u.x);
        q[f * 8 + 2] = bflo(u.y); q[f * 8 + 3] = bfhi(u.y);
        q[f * 8 + 4] = bflo(u.z); q[f * 8 + 5] = bfhi(u.z);
        q[f * 8 + 6] = bflo(u.w); q[f * 8 + 7] = bfhi(u.w);
    }
    // k rows pre-rotated: reg row s = global row (s + 4*pyh)&7 ; one uint4 per row
    #pragma unroll
    for (int s = 0; s < 8; ++s) {
        int r = (s + 4 * pyh) & 7;
        uint4 u = ((const uint4*)gk)[r];
        k[s * 8 + 0] = bflo(u.x); k[s * 8 + 1] = bfhi(u.x);
        k[s * 8 + 2] = bflo(u.y); k[s * 8 + 3] = bfhi(u.y);
        k[s * 8 + 4] = bflo(u.z); k[s * 8 + 5] = bfhi(u.z);
        k[s * 8 + 6] = bflo(u.w); k[s * 8 + 7] = bfhi(u.w);
    }
    float acc[4][8];
    #pragma unroll
    for (int it = 0; it < 4; ++it)
        #pragma unroll
        for (int px = 0; px < 8; ++px) acc[it][px] = 0.f;
    #pragma unroll
    for (int iy = 0; iy < 8; ++iy)
        #pragma unroll
        for (int ix = 0; ix < 8; ++ix) {
            float qv = q[iy * 8 + ix];
            #pragma unroll
            for (int it = 0; it < 4; ++it) {
                int ks = (it - iy) & 7;              // compile-time
                #pragma unroll
                for (int px = 0; px < 8; ++px)
                    acc[it][px] = fmaf(qv, k[ks * 8 + ((px - ix) & 7)], acc[it][px]);
            }
        }
    // transposed conv scratch: sC[c][pix], pad 68 (row stride 272 B, 16B-aligned)
    #pragma unroll
    for (int it = 0; it < 4; ++it) {
        int pix0 = pyh * 32 + it * 8;
        *(float4*)&sBuf[c * 68 + pix0] =
            make_float4(acc[it][0], acc[it][1], acc[it][2], acc[it][3]);
        *(float4*)&sBuf[c * 68 + pix0 + 4] =
            make_float4(acc[it][4], acc[it][5], acc[it][6], acc[it][7]);
    }
    // prefetch v (32 bf16 = 4 uint4)
    const uint4* gv = (const uint4*)(qkv + ((size_t)(b * 384 + 256 + c)) * QS
                                     + p * 64 + pyh * 32);
    float vv[32];
    #pragma unroll
    for (int f = 0; f < 4; ++f) {
        uint4 u = gv[f];
        vv[f * 8 + 0] = bflo(u.x); vv[f * 8 + 1] = bfhi(u.x);
        vv[f * 8 + 2] = bflo(u.y); vv[f * 8 + 3] = bfhi(u.y);
        vv[f * 8 + 4] = bflo(u.z); vv[f * 8 + 5] = bfhi(u.z);
        vv[f * 8 + 6] = bflo(u.w); vv[f * 8 + 7] = bfhi(u.w);
    }
    float lw = lnw[c], lb = lnb[c];
    __syncthreads();

    // P1: per-pixel channel reduction. Wave w owns pixels w*16..w*16+15;
    // lane bits 4..5 = channel-quarter -> butterfly within the wave.
    {
        int q4 = (t >> 4) & 3;
        int px = (t & 15) | ((t >> 6) << 4);
        float s = 0.f, s2 = 0.f;
        #pragma unroll
        for (int j = 0; j < 32; ++j) {
            float v = sBuf[(q4 * 32 + j) * 68 + px];
            s += v;
            s2 = fmaf(v, v, s2);
        }
        s  += __shfl_xor(s, 16);   s2 += __shfl_xor(s2, 16);
        s  += __shfl_xor(s, 32);   s2 += __shfl_xor(s2, 32);
        if ((t & 48) == 0) {
            float mu = s * (1.f / 128.f);
            float var = s2 * (1.f / 128.f) - mu * mu;
            sMu[px] = mu;
            sRstd[px] = rsqrtf(var + 1e-5f);
        }
    }
    __syncthreads();
    // P3: normalize from acc regs, * v, stage tvv as sT[pix][132] (c contiguous)
    #pragma unroll
    for (int it = 0; it < 4; ++it) {
        int pix0 = pyh * 32 + it * 8;
        float4 ma = *(const float4*)&sMu[pix0];
        float4 mb = *(const float4*)&sMu[pix0 + 4];
        float4 ra = *(const float4*)&sRstd[pix0];
        float4 rb = *(const float4*)&sRstd[pix0 + 4];
        float mus[8] = {ma.x, ma.y, ma.z, ma.w, mb.x, mb.y, mb.z, mb.w};
        float rss[8] = {ra.x, ra.y, ra.z, ra.w, rb.x, rb.y, rb.z, rb.w};
        #pragma unroll
        for (int px = 0; px < 8; ++px) {
            float tv = fmaf((acc[it][px] - mus[px]) * rss[px], lw, lb)
                       * vv[it * 8 + px];
            sBuf[(pix0 + px) * 132 + c] = tv;
        }
    }
    __syncthreads();
    // P4: proj 128->64, tvv read as float4 (4 channels / ds_read_b128)
    {
        int px = t & 63;
        int og = __builtin_amdgcn_readfirstlane((t >> 6) * 16);
        float po[16];
        #pragma unroll
        for (int j = 0; j < 16; ++j) po[j] = 0.f;
        const float4* tb = (const float4*)&sBuf[px * 132];
        #pragma unroll 4
        for (int k4 = 0; k4 < 32; ++k4) {
            float4 tv = tb[k4];
            const float* w0 = wpT + (k4 * 4 + 0) * 64 + og;
            const float* w1 = wpT + (k4 * 4 + 1) * 64 + og;
            const float* w2 = wpT + (k4 * 4 + 2) * 64 + og;
            const float* w3 = wpT + (k4 * 4 + 3) * 64 + og;
            #pragma unroll
            for (int j = 0; j < 16; ++j)
                po[j] = fmaf(w0[j], tv.x,
                        fmaf(w1[j], tv.y,
                        fmaf(w2[j], tv.z,
                        fmaf(w3[j], tv.w, po[j]))));
        }
        int grow = r0 + (p >> 5) * 8 + (px >> 3);
        int gcol = (p & 31) * 8 + (px & 7);
        float* ob = outp + ((size_t)(b * 64 + og)) * HW + grow * 256 + gcol;
        #pragma unroll
        for (int j = 0; j < 16; ++j) ob[(size_t)j * HW] = po[j];
    }
}

extern "C" void kernel_launch(void* const* d_in, const int* in_sizes, int n_in,
                              void* d_out, int out_size, void* d_ws, size_t ws_size,
                              hipStream_t stream) {
    const float* x     = (const float*)d_in[0];
    const float* prior = (const float*)d_in[1];
    const float* wk    = (const float*)d_in[2];
    const float* wh    = (const float*)d_in[3];
    const float* wdw   = (const float*)d_in[4];
    const float* wp    = (const float*)d_in[5];
    const float* lnw   = (const float*)d_in[6];
    const float* lnb   = (const float*)d_in[7];
    float* out = (float*)d_out;
    float* ws  = (float*)d_ws;

    float* kv  = ws;
    float* whT = ws + 512;
    float* wpT = ws + 512 + 24576;
    unsigned short* hid = (unsigned short*)(ws + 40960);        // [4][384][66][256] bf16
    unsigned short* qkv = hid + (size_t)4 * 384 * HSZ2;         // [4][384][256][64] bf16

    k_prep<<<dim3(130), dim3(256), 0, stream>>>(prior, wk, wh, wp, kv, whT, wpT);
    for (int slab = 0; slab < 4; ++slab) {
        int r0 = slab * SLAB;
        k2_hidden<<<dim3(HROWS, 4, 4), dim3(256), 0, stream>>>(x, whT, kv, hid, r0);
        k3_dw<<<dim3(8, 192, 4), dim3(256), 0, stream>>>(hid, wdw, qkv);
        kC_patch<<<dim3(256, 4), dim3(256), 0, stream>>>(qkv, wpT, lnw, lnb, out, r0);
    }
}

// Round 9
// 651.863 us; speedup vs baseline: 2.0385x; 2.0385x over previous
//
#include <hip/hip_runtime.h>

// FSAS slab pipeline, 4 slabs of 64 rows, bf16 intermediates:
//   k2: affine(kv) + 1x1 conv 64->384 -> hid bf16 slab (66 rows incl. halo)
//       v6: = v5 (LDS-staged xp, x read once) + readfirstlane(wv) so weight
//       loads stay SCALAR (v5 bug: thread-derived wv demoted them to vector
//       loads -> SGPR 32, VALUBusy 12%, 238us/slab).
//   k3: grouped 3x3 -> qkv bf16 slab, PATCHIFIED [ch][patch(256)][64]
//       v2: 32-row x 64-col tiles
//   kC: per-patch circular conv (q,k in VGPRs) + LN + *v + proj 128->64 -> out
// Workspace:
//   kv  fp32 @ 0      (512)
//   whT fp32 @ 512    (24576)  whT[c*384+o] = w_hidden[o][c]
//   wpT fp32 @ 25088  (8192)   wpT[c*64+o]  = w_proj[o][c]
//   hid bf16 @ float-ofs 40960 : [4][384][66][256]  (51.9 MB)
//   qkv bf16 after hid          : [4][384][256][64]  (50.3 MB)
// Total 102,400,000 B = 97.66 MiB (< proven 99.15 MiB).

#define HW    65536
#define SLAB  64
#define HROWS 66
#define HSZ2  (HROWS*256)   // bf16 elems per (b,ch) hid plane
#define QS    16384         // bf16 elems per (b,ch) qkv plane (256 patches * 64)

__device__ __forceinline__ unsigned short f2bf(float f) {
    unsigned u = __float_as_uint(f);
    u += 0x7FFFu + ((u >> 16) & 1u);       // RNE
    return (unsigned short)(u >> 16);
}
__device__ __forceinline__ float bflo(unsigned u) { return __uint_as_float(u << 16); }
__device__ __forceinline__ float bfhi(unsigned u) { return __uint_as_float(u & 0xFFFF0000u); }

__global__ void k_prep(const float* __restrict__ prior, const float* __restrict__ wk,
                       const float* __restrict__ wh, const float* __restrict__ wp,
                       float* __restrict__ kv, float* __restrict__ whT, float* __restrict__ wpT) {
    int t = blockIdx.x * 256 + threadIdx.x;
    if (t < 512) {
        int b = t >> 7, k = t & 127;
        const float* p = prior + b * 192;
        const float* w = wk + k * 192;
        float s = 0.f;
        for (int f = 0; f < 192; ++f) s = fmaf(p[f], w[f], s);
        kv[t] = s;
        return;
    }
    t -= 512;
    if (t < 24576) {
        int c = t / 384, o = t - c * 384;
        whT[t] = wh[o * 64 + c];
        return;
    }
    t -= 24576;
    int c = t >> 6, o = t & 63;
    wpT[t] = wp[o * 128 + c];
}

// v6: block = (row, col-quarter, b). Stage xp[64ch][64px] in LDS (affine fused,
// coalesced float2), then wave wv (readfirstlane -> SGPR, provably uniform)
// computes out-ch wv*96..wv*96+95 in 3 iters of acc[32]. x read once per slab.
// Weights via wave-uniform SCALAR loads; LDS reads conflict-free (row-contig).
__global__ __launch_bounds__(256, 4) void k2_hidden(const float* __restrict__ x,
    const float* __restrict__ whT, const float* __restrict__ kv,
    unsigned short* __restrict__ hid, int r0) {
    __shared__ float sXp[64 * 64];   // 16 KB
    int t = threadIdx.x;
    int row = blockIdx.x;            // 0..65
    int colq = blockIdx.y;           // 0..3
    int b = blockIdx.z;
    int col0 = colq * 64;
    int g = r0 - 1 + row;
    int px = t & 63;
    int wv = __builtin_amdgcn_readfirstlane(t >> 6);   // SGPR -> scalar weight path
    unsigned short* hb = hid + ((size_t)(b * 384 + wv * 96)) * HSZ2
                         + row * 256 + col0 + px;
    if (g < 0 || g > 255) {          // block-uniform edge path (no barrier here)
        #pragma unroll
        for (int it = 0; it < 3; ++it)
            #pragma unroll
            for (int j = 0; j < 32; ++j)
                hb[(size_t)(it * 32 + j) * HSZ2] = 0;
        return;
    }
    const float* kv1 = kv + b * 128;
    const float* kv2 = kv1 + 64;
    const float2* xb = (const float2*)(x + (size_t)b * 64 * HW + (size_t)g * 256 + col0);
    #pragma unroll
    for (int i = 0; i < 8; ++i) {    // 2048 float2 = 64ch x 32
        int idx = t + i * 256;
        int c = idx >> 5;            // 0..63
        int l2 = idx & 31;
        float2 xv = xb[(size_t)c * (HW / 2) + l2];
        float2 s;
        s.x = fmaf(xv.x, kv1[c], kv2[c]);
        s.y = fmaf(xv.y, kv1[c], kv2[c]);
        *(float2*)&sXp[c * 64 + l2 * 2] = s;
    }
    __syncthreads();
    #pragma unroll
    for (int it = 0; it < 3; ++it) {
        int obase = wv * 96 + it * 32;          // SGPR-uniform
        const float* wbase = whT + obase;
        float acc[32];
        #pragma unroll
        for (int j = 0; j < 32; ++j) acc[j] = 0.f;
        #pragma unroll 4
        for (int c = 0; c < 64; ++c) {
            float xv = sXp[c * 64 + px];
            const float* wr = wbase + c * 384;  // wave-uniform -> scalar loads
            #pragma unroll
            for (int j = 0; j < 32; ++j)
                acc[j] = fmaf(wr[j], xv, acc[j]);
        }
        #pragma unroll
        for (int j = 0; j < 32; ++j)
            hb[(size_t)(it * 32 + j) * HSZ2] = f2bf(acc[j]);
    }
}

// grouped 3x3 conv from bf16 hid -> bf16 qkv patchified [ch][patch][py*8+px]
// v2: 32-row x 64-col tile per block (halo 34x66), 4 pp-passes, 288 fma/thread.
__global__ __launch_bounds__(256) void k3_dw(const unsigned short* __restrict__ hid,
    const float* __restrict__ wdw, unsigned short* __restrict__ qkv) {
    __shared__ float sIn[2 * 34 * 66];
    int t = threadIdx.x;
    int bid = blockIdx.x;            // 8 tiles: tx 0..3 (x64 cols), ty 0..1 (x32 rows)
    int gl = blockIdx.y;             // 0..191
    int b = blockIdx.z;
    int tx = bid & 3, ty = bid >> 2;
    int x0 = tx * 64, y0 = ty * 32;
    const unsigned short* hbase = hid + ((size_t)(b * 384 + 2 * gl)) * HSZ2;
    for (int idx = t; idx < 2 * 34 * 66; idx += 256) {
        int chl = idx >= 2244;
        int rem = idx - chl * 2244;
        int row = rem / 66;
        int col = rem - row * 66;
        int gx = x0 + col - 1;
        float v = 0.f;
        if (gx >= 0 && gx < 256)
            v = bflo((unsigned)hbase[(size_t)chl * HSZ2 + (y0 + row) * 256 + gx]);
        sIn[idx] = v;
    }
    __syncthreads();
    int og = 2 * gl;
    float w0[18], w1[18];
    #pragma unroll
    for (int i = 0; i < 18; ++i) {
        w0[i] = wdw[(size_t)og * 18 + i];
        w1[i] = wdw[(size_t)(og + 1) * 18 + i];
    }
    unsigned short* q0 = qkv + ((size_t)(b * 384 + og)) * QS;
    #pragma unroll
    for (int pp = 0; pp < 4; ++pp) {
        int ly = pp * 8 + (t >> 5);                  // 0..31
        int lxp = (t & 31) * 2;                      // even col in tile
        float a[2][2];                               // [px][out-ch]
        #pragma unroll
        for (int px = 0; px < 2; ++px) {
            float s0 = 0.f, s1 = 0.f;
            #pragma unroll
            for (int i = 0; i < 2; ++i)
                #pragma unroll
                for (int ky = 0; ky < 3; ++ky)
                    #pragma unroll
                    for (int kx = 0; kx < 3; ++kx) {
                        float v = sIn[i * 2244 + (ly + ky) * 66 + (lxp + px + kx)];
                        s0 = fmaf(w0[i * 9 + ky * 3 + kx], v, s0);
                        s1 = fmaf(w1[i * 9 + ky * 3 + kx], v, s1);
                    }
            a[px][0] = s0; a[px][1] = s1;
        }
        int row = y0 + ly;                           // slab row 0..63
        int gx = x0 + lxp;
        int patch = (row >> 3) * 32 + (gx >> 3);     // 0..255
        int off = patch * 64 + (row & 7) * 8 + (gx & 7);   // even
        ((unsigned*)(q0 + off))[0] =
            (unsigned)f2bf(a[0][0]) | ((unsigned)f2bf(a[1][0]) << 16);
        ((unsigned*)(q0 + QS + off))[0] =
            (unsigned)f2bf(a[0][1]) | ((unsigned)f2bf(a[1][1]) << 16);
    }
}

// Fused per-patch: circular conv (q,k in regs) + LN(128) + *v + proj 128->64.
// Thread t: channel c = t&127, py-half pyh = t>>7.
// v2 dataflow: 3 barriers, no serial phase.
//   P0 conv -> sC[c][68] (float4 writes, transposed)
//   P1 reduce over c: (q4,px) mapping, 4 partials per pixel live in ONE wave,
//      combined with 2x shfl_xor -> sMu/sRstd (no sRed arrays, no t<64 phase)
//   P3 normalize from acc regs -> tvv to sT[pix][132] (aliases sC)
//   P4 proj: ds_read_b128 over channels (4/instr), weights via SGPR
__global__ __launch_bounds__(256, 2) void kC_patch(const unsigned short* __restrict__ qkv,
    const float* __restrict__ wpT, const float* __restrict__ lnw,
    const float* __restrict__ lnb, float* __restrict__ outp, int r0) {
    __shared__ __align__(16) float sBuf[128 * 68];   // P0/P1: sC[c][68]; P3/P4: sT[pix][132]
    __shared__ __align__(16) float sMu[64];
    __shared__ __align__(16) float sRstd[64];
    int t = threadIdx.x;
    int p = blockIdx.x;              // slab-local patch 0..255
    int b = blockIdx.y;
    int c = t & 127;
    int pyh = t >> 7;

    const uint4* gq = (const uint4*)(qkv + ((size_t)(b * 384 + c)) * QS + p * 64);
    const uint4* gk = (const uint4*)(qkv + ((size_t)(b * 384 + 128 + c)) * QS + p * 64);
    float q[64], k[64];
    #pragma unroll
    for (int f = 0; f < 8; ++f) {                     // 8 bf16 per uint4
        uint4 u = gq[f];
        q[f * 8 + 0] = bflo(u.x); q[f * 8 + 1] = bfhi(u.x);
        q[f * 8 + 2] = bflo(u.y); q[f * 8 + 3] = bfhi(u.y);
        q[f * 8 + 4] = bflo(u.z); q[f * 8 + 5] = bfhi(u.z);
        q[f * 8 + 6] = bflo(u.w); q[f * 8 + 7] = bfhi(u.w);
    }
    // k rows pre-rotated: reg row s = global row (s + 4*pyh)&7 ; one uint4 per row
    #pragma unroll
    for (int s = 0; s < 8; ++s) {
        int r = (s + 4 * pyh) & 7;
        uint4 u = ((const uint4*)gk)[r];
        k[s * 8 + 0] = bflo(u.x); k[s * 8 + 1] = bfhi(u.x);
        k[s * 8 + 2] = bflo(u.y); k[s * 8 + 3] = bfhi(u.y);
        k[s * 8 + 4] = bflo(u.z); k[s * 8 + 5] = bfhi(u.z);
        k[s * 8 + 6] = bflo(u.w); k[s * 8 + 7] = bfhi(u.w);
    }
    float acc[4][8];
    #pragma unroll
    for (int it = 0; it < 4; ++it)
        #pragma unroll
        for (int px = 0; px < 8; ++px) acc[it][px] = 0.f;
    #pragma unroll
    for (int iy = 0; iy < 8; ++iy)
        #pragma unroll
        for (int ix = 0; ix < 8; ++ix) {
            float qv = q[iy * 8 + ix];
            #pragma unroll
            for (int it = 0; it < 4; ++it) {
                int ks = (it - iy) & 7;              // compile-time
                #pragma unroll
                for (int px = 0; px < 8; ++px)
                    acc[it][px] = fmaf(qv, k[ks * 8 + ((px - ix) & 7)], acc[it][px]);
            }
        }
    // transposed conv scratch: sC[c][pix], pad 68 (row stride 272 B, 16B-aligned)
    #pragma unroll
    for (int it = 0; it < 4; ++it) {
        int pix0 = pyh * 32 + it * 8;
        *(float4*)&sBuf[c * 68 + pix0] =
            make_float4(acc[it][0], acc[it][1], acc[it][2], acc[it][3]);
        *(float4*)&sBuf[c * 68 + pix0 + 4] =
            make_float4(acc[it][4], acc[it][5], acc[it][6], acc[it][7]);
    }
    // prefetch v (32 bf16 = 4 uint4)
    const uint4* gv = (const uint4*)(qkv + ((size_t)(b * 384 + 256 + c)) * QS
                                     + p * 64 + pyh * 32);
    float vv[32];
    #pragma unroll
    for (int f = 0; f < 4; ++f) {
        uint4 u = gv[f];
        vv[f * 8 + 0] = bflo(u.x); vv[f * 8 + 1] = bfhi(u.x);
        vv[f * 8 + 2] = bflo(u.y); vv[f * 8 + 3] = bfhi(u.y);
        vv[f * 8 + 4] = bflo(u.z); vv[f * 8 + 5] = bfhi(u.z);
        vv[f * 8 + 6] = bflo(u.w); vv[f * 8 + 7] = bfhi(u.w);
    }
    float lw = lnw[c], lb = lnb[c];
    __syncthreads();

    // P1: per-pixel channel reduction. Wave w owns pixels w*16..w*16+15;
    // lane bits 4..5 = channel-quarter -> butterfly within the wave.
    {
        int q4 = (t >> 4) & 3;
        int px = (t & 15) | ((t >> 6) << 4);
        float s = 0.f, s2 = 0.f;
        #pragma unroll
        for (int j = 0; j < 32; ++j) {
            float v = sBuf[(q4 * 32 + j) * 68 + px];
            s += v;
            s2 = fmaf(v, v, s2);
        }
        s  += __shfl_xor(s, 16);   s2 += __shfl_xor(s2, 16);
        s  += __shfl_xor(s, 32);   s2 += __shfl_xor(s2, 32);
        if ((t & 48) == 0) {
            float mu = s * (1.f / 128.f);
            float var = s2 * (1.f / 128.f) - mu * mu;
            sMu[px] = mu;
            sRstd[px] = rsqrtf(var + 1e-5f);
        }
    }
    __syncthreads();
    // P3: normalize from acc regs, * v, stage tvv as sT[pix][132] (c contiguous)
    #pragma unroll
    for (int it = 0; it < 4; ++it) {
        int pix0 = pyh * 32 + it * 8;
        float4 ma = *(const float4*)&sMu[pix0];
        float4 mb = *(const float4*)&sMu[pix0 + 4];
        float4 ra = *(const float4*)&sRstd[pix0];
        float4 rb = *(const float4*)&sRstd[pix0 + 4];
        float mus[8] = {ma.x, ma.y, ma.z, ma.w, mb.x, mb.y, mb.z, mb.w};
        float rss[8] = {ra.x, ra.y, ra.z, ra.w, rb.x, rb.y, rb.z, rb.w};
        #pragma unroll
        for (int px = 0; px < 8; ++px) {
            float tv = fmaf((acc[it][px] - mus[px]) * rss[px], lw, lb)
                       * vv[it * 8 + px];
            sBuf[(pix0 + px) * 132 + c] = tv;
        }
    }
    __syncthreads();
    // P4: proj 128->64, tvv read as float4 (4 channels / ds_read_b128)
    {
        int px = t & 63;
        int og = __builtin_amdgcn_readfirstlane((t >> 6) * 16);
        float po[16];
        #pragma unroll
        for (int j = 0; j < 16; ++j) po[j] = 0.f;
        const float4* tb = (const float4*)&sBuf[px * 132];
        #pragma unroll 4
        for (int k4 = 0; k4 < 32; ++k4) {
            float4 tv = tb[k4];
            const float* w0 = wpT + (k4 * 4 + 0) * 64 + og;
            const float* w1 = wpT + (k4 * 4 + 1) * 64 + og;
            const float* w2 = wpT + (k4 * 4 + 2) * 64 + og;
            const float* w3 = wpT + (k4 * 4 + 3) * 64 + og;
            #pragma unroll
            for (int j = 0; j < 16; ++j)
                po[j] = fmaf(w0[j], tv.x,
                        fmaf(w1[j], tv.y,
                        fmaf(w2[j], tv.z,
                        fmaf(w3[j], tv.w, po[j]))));
        }
        int grow = r0 + (p >> 5) * 8 + (px >> 3);
        int gcol = (p & 31) * 8 + (px & 7);
        float* ob = outp + ((size_t)(b * 64 + og)) * HW + grow * 256 + gcol;
        #pragma unroll
        for (int j = 0; j < 16; ++j) ob[(size_t)j * HW] = po[j];
    }
}

extern "C" void kernel_launch(void* const* d_in, const int* in_sizes, int n_in,
                              void* d_out, int out_size, void* d_ws, size_t ws_size,
                              hipStream_t stream) {
    const float* x     = (const float*)d_in[0];
    const float* prior = (const float*)d_in[1];
    const float* wk    = (const float*)d_in[2];
    const float* wh    = (const float*)d_in[3];
    const float* wdw   = (const float*)d_in[4];
    const float* wp    = (const float*)d_in[5];
    const float* lnw   = (const float*)d_in[6];
    const float* lnb   = (const float*)d_in[7];
    float* out = (float*)d_out;
    float* ws  = (float*)d_ws;

    float* kv  = ws;
    float* whT = ws + 512;
    float* wpT = ws + 512 + 24576;
    unsigned short* hid = (unsigned short*)(ws + 40960);        // [4][384][66][256] bf16
    unsigned short* qkv = hid + (size_t)4 * 384 * HSZ2;         // [4][384][256][64] bf16

    k_prep<<<dim3(130), dim3(256), 0, stream>>>(prior, wk, wh, wp, kv, whT, wpT);
    for (int slab = 0; slab < 4; ++slab) {
        int r0 = slab * SLAB;
        k2_hidden<<<dim3(HROWS, 4, 4), dim3(256), 0, stream>>>(x, whT, kv, hid, r0);
        k3_dw<<<dim3(8, 192, 4), dim3(256), 0, stream>>>(hid, wdw, qkv);
        kC_patch<<<dim3(256, 4), dim3(256), 0, stream>>>(qkv, wpT, lnw, lnb, out, r0);
    }
}

// Round 10
// 627.334 us; speedup vs baseline: 2.1182x; 1.0391x over previous
//
#include <hip/hip_runtime.h>

// FSAS slab pipeline, 4 slabs of 64 rows, bf16 intermediates:
//   k2: affine(kv) + 1x1 conv 64->384 -> hid bf16 slab (66 rows incl. halo)
//       v7: v6 + out-ch split (grid.z = b*2+half): 2112 blocks, wave = 48 ch
//       (3x acc[16]) -> ~2x resident waves for lgkmcnt latency hiding.
//   k3: grouped 3x3 -> qkv bf16 slab, PATCHIFIED [ch][patch(256)][64]
//       v2: 32-row x 64-col tiles
//   kC: per-patch circular conv (q,k in VGPRs) + LN + *v + proj 128->64 -> out
// Workspace:
//   kv  fp32 @ 0      (512)
//   whT fp32 @ 512    (24576)  whT[c*384+o] = w_hidden[o][c]
//   wpT fp32 @ 25088  (8192)   wpT[c*64+o]  = w_proj[o][c]
//   hid bf16 @ float-ofs 40960 : [4][384][66][256]  (51.9 MB)
//   qkv bf16 after hid          : [4][384][256][64]  (50.3 MB)
// Total 102,400,000 B = 97.66 MiB (< proven 99.15 MiB).

#define HW    65536
#define SLAB  64
#define HROWS 66
#define HSZ2  (HROWS*256)   // bf16 elems per (b,ch) hid plane
#define QS    16384         // bf16 elems per (b,ch) qkv plane (256 patches * 64)

__device__ __forceinline__ unsigned short f2bf(float f) {
    unsigned u = __float_as_uint(f);
    u += 0x7FFFu + ((u >> 16) & 1u);       // RNE
    return (unsigned short)(u >> 16);
}
__device__ __forceinline__ float bflo(unsigned u) { return __uint_as_float(u << 16); }
__device__ __forceinline__ float bfhi(unsigned u) { return __uint_as_float(u & 0xFFFF0000u); }

__global__ void k_prep(const float* __restrict__ prior, const float* __restrict__ wk,
                       const float* __restrict__ wh, const float* __restrict__ wp,
                       float* __restrict__ kv, float* __restrict__ whT, float* __restrict__ wpT) {
    int t = blockIdx.x * 256 + threadIdx.x;
    if (t < 512) {
        int b = t >> 7, k = t & 127;
        const float* p = prior + b * 192;
        const float* w = wk + k * 192;
        float s = 0.f;
        for (int f = 0; f < 192; ++f) s = fmaf(p[f], w[f], s);
        kv[t] = s;
        return;
    }
    t -= 512;
    if (t < 24576) {
        int c = t / 384, o = t - c * 384;
        whT[t] = wh[o * 64 + c];
        return;
    }
    t -= 24576;
    int c = t >> 6, o = t & 63;
    wpT[t] = wp[o * 128 + c];
}

// v7: block = (row, col-quarter, b*2+half). Stage xp[64ch][64px] in LDS (affine
// fused, coalesced float2), then wave wv (readfirstlane -> SGPR) computes
// out-ch half*192 + wv*48 .. +47 in 3 iters of acc[16]. Weights scalar-loaded.
__global__ __launch_bounds__(256, 4) void k2_hidden(const float* __restrict__ x,
    const float* __restrict__ whT, const float* __restrict__ kv,
    unsigned short* __restrict__ hid, int r0) {
    __shared__ float sXp[64 * 64];   // 16 KB
    int t = threadIdx.x;
    int row = blockIdx.x;            // 0..65
    int colq = blockIdx.y;           // 0..3
    int z = blockIdx.z;              // 0..7
    int b = z >> 1;
    int half = z & 1;
    int col0 = colq * 64;
    int g = r0 - 1 + row;
    int px = t & 63;
    int wv = __builtin_amdgcn_readfirstlane(t >> 6);   // SGPR -> scalar weight path
    int och0 = half * 192 + wv * 48;
    unsigned short* hb = hid + ((size_t)(b * 384 + och0)) * HSZ2
                         + row * 256 + col0 + px;
    if (g < 0 || g > 255) {          // block-uniform edge path (no barrier here)
        #pragma unroll
        for (int it = 0; it < 3; ++it)
            #pragma unroll
            for (int j = 0; j < 16; ++j)
                hb[(size_t)(it * 16 + j) * HSZ2] = 0;
        return;
    }
    const float* kv1 = kv + b * 128;
    const float* kv2 = kv1 + 64;
    const float2* xb = (const float2*)(x + (size_t)b * 64 * HW + (size_t)g * 256 + col0);
    #pragma unroll
    for (int i = 0; i < 8; ++i) {    // 2048 float2 = 64ch x 32
        int idx = t + i * 256;
        int c = idx >> 5;            // 0..63
        int l2 = idx & 31;
        float2 xv = xb[(size_t)c * (HW / 2) + l2];
        float2 s;
        s.x = fmaf(xv.x, kv1[c], kv2[c]);
        s.y = fmaf(xv.y, kv1[c], kv2[c]);
        *(float2*)&sXp[c * 64 + l2 * 2] = s;
    }
    __syncthreads();
    #pragma unroll
    for (int it = 0; it < 3; ++it) {
        const float* wbase = whT + och0 + it * 16;   // SGPR-uniform
        float acc[16];
        #pragma unroll
        for (int j = 0; j < 16; ++j) acc[j] = 0.f;
        #pragma unroll 4
        for (int c = 0; c < 64; ++c) {
            float xv = sXp[c * 64 + px];
            const float* wr = wbase + c * 384;       // wave-uniform -> scalar loads
            #pragma unroll
            for (int j = 0; j < 16; ++j)
                acc[j] = fmaf(wr[j], xv, acc[j]);
        }
        #pragma unroll
        for (int j = 0; j < 16; ++j)
            hb[(size_t)(it * 16 + j) * HSZ2] = f2bf(acc[j]);
    }
}

// grouped 3x3 conv from bf16 hid -> bf16 qkv patchified [ch][patch][py*8+px]
// v2: 32-row x 64-col tile per block (halo 34x66), 4 pp-passes, 288 fma/thread.
__global__ __launch_bounds__(256) void k3_dw(const unsigned short* __restrict__ hid,
    const float* __restrict__ wdw, unsigned short* __restrict__ qkv) {
    __shared__ float sIn[2 * 34 * 66];
    int t = threadIdx.x;
    int bid = blockIdx.x;            // 8 tiles: tx 0..3 (x64 cols), ty 0..1 (x32 rows)
    int gl = blockIdx.y;             // 0..191
    int b = blockIdx.z;
    int tx = bid & 3, ty = bid >> 2;
    int x0 = tx * 64, y0 = ty * 32;
    const unsigned short* hbase = hid + ((size_t)(b * 384 + 2 * gl)) * HSZ2;
    for (int idx = t; idx < 2 * 34 * 66; idx += 256) {
        int chl = idx >= 2244;
        int rem = idx - chl * 2244;
        int row = rem / 66;
        int col = rem - row * 66;
        int gx = x0 + col - 1;
        float v = 0.f;
        if (gx >= 0 && gx < 256)
            v = bflo((unsigned)hbase[(size_t)chl * HSZ2 + (y0 + row) * 256 + gx]);
        sIn[idx] = v;
    }
    __syncthreads();
    int og = 2 * gl;
    float w0[18], w1[18];
    #pragma unroll
    for (int i = 0; i < 18; ++i) {
        w0[i] = wdw[(size_t)og * 18 + i];
        w1[i] = wdw[(size_t)(og + 1) * 18 + i];
    }
    unsigned short* q0 = qkv + ((size_t)(b * 384 + og)) * QS;
    #pragma unroll
    for (int pp = 0; pp < 4; ++pp) {
        int ly = pp * 8 + (t >> 5);                  // 0..31
        int lxp = (t & 31) * 2;                      // even col in tile
        float a[2][2];                               // [px][out-ch]
        #pragma unroll
        for (int px = 0; px < 2; ++px) {
            float s0 = 0.f, s1 = 0.f;
            #pragma unroll
            for (int i = 0; i < 2; ++i)
                #pragma unroll
                for (int ky = 0; ky < 3; ++ky)
                    #pragma unroll
                    for (int kx = 0; kx < 3; ++kx) {
                        float v = sIn[i * 2244 + (ly + ky) * 66 + (lxp + px + kx)];
                        s0 = fmaf(w0[i * 9 + ky * 3 + kx], v, s0);
                        s1 = fmaf(w1[i * 9 + ky * 3 + kx], v, s1);
                    }
            a[px][0] = s0; a[px][1] = s1;
        }
        int row = y0 + ly;                           // slab row 0..63
        int gx = x0 + lxp;
        int patch = (row >> 3) * 32 + (gx >> 3);     // 0..255
        int off = patch * 64 + (row & 7) * 8 + (gx & 7);   // even
        ((unsigned*)(q0 + off))[0] =
            (unsigned)f2bf(a[0][0]) | ((unsigned)f2bf(a[1][0]) << 16);
        ((unsigned*)(q0 + QS + off))[0] =
            (unsigned)f2bf(a[0][1]) | ((unsigned)f2bf(a[1][1]) << 16);
    }
}

// Fused per-patch: circular conv (q,k in regs) + LN(128) + *v + proj 128->64.
// Thread t: channel c = t&127, py-half pyh = t>>7.
// v2 dataflow: 3 barriers, no serial phase.
//   P0 conv -> sC[c][68] (float4 writes, transposed)
//   P1 reduce over c: (q4,px) mapping, 4 partials per pixel live in ONE wave,
//      combined with 2x shfl_xor -> sMu/sRstd (no sRed arrays, no t<64 phase)
//   P3 normalize from acc regs -> tvv to sT[pix][132] (aliases sC)
//   P4 proj: ds_read_b128 over channels (4/instr), weights via SGPR
__global__ __launch_bounds__(256, 2) void kC_patch(const unsigned short* __restrict__ qkv,
    const float* __restrict__ wpT, const float* __restrict__ lnw,
    const float* __restrict__ lnb, float* __restrict__ outp, int r0) {
    __shared__ __align__(16) float sBuf[128 * 68];   // P0/P1: sC[c][68]; P3/P4: sT[pix][132]
    __shared__ __align__(16) float sMu[64];
    __shared__ __align__(16) float sRstd[64];
    int t = threadIdx.x;
    int p = blockIdx.x;              // slab-local patch 0..255
    int b = blockIdx.y;
    int c = t & 127;
    int pyh = t >> 7;

    const uint4* gq = (const uint4*)(qkv + ((size_t)(b * 384 + c)) * QS + p * 64);
    const uint4* gk = (const uint4*)(qkv + ((size_t)(b * 384 + 128 + c)) * QS + p * 64);
    float q[64], k[64];
    #pragma unroll
    for (int f = 0; f < 8; ++f) {                     // 8 bf16 per uint4
        uint4 u = gq[f];
        q[f * 8 + 0] = bflo(u.x); q[f * 8 + 1] = bfhi(u.x);
        q[f * 8 + 2] = bflo(u.y); q[f * 8 + 3] = bfhi(u.y);
        q[f * 8 + 4] = bflo(u.z); q[f * 8 + 5] = bfhi(u.z);
        q[f * 8 + 6] = bflo(u.w); q[f * 8 + 7] = bfhi(u.w);
    }
    // k rows pre-rotated: reg row s = global row (s + 4*pyh)&7 ; one uint4 per row
    #pragma unroll
    for (int s = 0; s < 8; ++s) {
        int r = (s + 4 * pyh) & 7;
        uint4 u = ((const uint4*)gk)[r];
        k[s * 8 + 0] = bflo(u.x); k[s * 8 + 1] = bfhi(u.x);
        k[s * 8 + 2] = bflo(u.y); k[s * 8 + 3] = bfhi(u.y);
        k[s * 8 + 4] = bflo(u.z); k[s * 8 + 5] = bfhi(u.z);
        k[s * 8 + 6] = bflo(u.w); k[s * 8 + 7] = bfhi(u.w);
    }
    float acc[4][8];
    #pragma unroll
    for (int it = 0; it < 4; ++it)
        #pragma unroll
        for (int px = 0; px < 8; ++px) acc[it][px] = 0.f;
    #pragma unroll
    for (int iy = 0; iy < 8; ++iy)
        #pragma unroll
        for (int ix = 0; ix < 8; ++ix) {
            float qv = q[iy * 8 + ix];
            #pragma unroll
            for (int it = 0; it < 4; ++it) {
                int ks = (it - iy) & 7;              // compile-time
                #pragma unroll
                for (int px = 0; px < 8; ++px)
                    acc[it][px] = fmaf(qv, k[ks * 8 + ((px - ix) & 7)], acc[it][px]);
            }
        }
    // transposed conv scratch: sC[c][pix], pad 68 (row stride 272 B, 16B-aligned)
    #pragma unroll
    for (int it = 0; it < 4; ++it) {
        int pix0 = pyh * 32 + it * 8;
        *(float4*)&sBuf[c * 68 + pix0] =
            make_float4(acc[it][0], acc[it][1], acc[it][2], acc[it][3]);
        *(float4*)&sBuf[c * 68 + pix0 + 4] =
            make_float4(acc[it][4], acc[it][5], acc[it][6], acc[it][7]);
    }
    // prefetch v (32 bf16 = 4 uint4)
    const uint4* gv = (const uint4*)(qkv + ((size_t)(b * 384 + 256 + c)) * QS
                                     + p * 64 + pyh * 32);
    float vv[32];
    #pragma unroll
    for (int f = 0; f < 4; ++f) {
        uint4 u = gv[f];
        vv[f * 8 + 0] = bflo(u.x); vv[f * 8 + 1] = bfhi(u.x);
        vv[f * 8 + 2] = bflo(u.y); vv[f * 8 + 3] = bfhi(u.y);
        vv[f * 8 + 4] = bflo(u.z); vv[f * 8 + 5] = bfhi(u.z);
        vv[f * 8 + 6] = bflo(u.w); vv[f * 8 + 7] = bfhi(u.w);
    }
    float lw = lnw[c], lb = lnb[c];
    __syncthreads();

    // P1: per-pixel channel reduction. Wave w owns pixels w*16..w*16+15;
    // lane bits 4..5 = channel-quarter -> butterfly within the wave.
    {
        int q4 = (t >> 4) & 3;
        int px = (t & 15) | ((t >> 6) << 4);
        float s = 0.f, s2 = 0.f;
        #pragma unroll
        for (int j = 0; j < 32; ++j) {
            float v = sBuf[(q4 * 32 + j) * 68 + px];
            s += v;
            s2 = fmaf(v, v, s2);
        }
        s  += __shfl_xor(s, 16);   s2 += __shfl_xor(s2, 16);
        s  += __shfl_xor(s, 32);   s2 += __shfl_xor(s2, 32);
        if ((t & 48) == 0) {
            float mu = s * (1.f / 128.f);
            float var = s2 * (1.f / 128.f) - mu * mu;
            sMu[px] = mu;
            sRstd[px] = rsqrtf(var + 1e-5f);
        }
    }
    __syncthreads();
    // P3: normalize from acc regs, * v, stage tvv as sT[pix][132] (c contiguous)
    #pragma unroll
    for (int it = 0; it < 4; ++it) {
        int pix0 = pyh * 32 + it * 8;
        float4 ma = *(const float4*)&sMu[pix0];
        float4 mb = *(const float4*)&sMu[pix0 + 4];
        float4 ra = *(const float4*)&sRstd[pix0];
        float4 rb = *(const float4*)&sRstd[pix0 + 4];
        float mus[8] = {ma.x, ma.y, ma.z, ma.w, mb.x, mb.y, mb.z, mb.w};
        float rss[8] = {ra.x, ra.y, ra.z, ra.w, rb.x, rb.y, rb.z, rb.w};
        #pragma unroll
        for (int px = 0; px < 8; ++px) {
            float tv = fmaf((acc[it][px] - mus[px]) * rss[px], lw, lb)
                       * vv[it * 8 + px];
            sBuf[(pix0 + px) * 132 + c] = tv;
        }
    }
    __syncthreads();
    // P4: proj 128->64, tvv read as float4 (4 channels / ds_read_b128)
    {
        int px = t & 63;
        int og = __builtin_amdgcn_readfirstlane((t >> 6) * 16);
        float po[16];
        #pragma unroll
        for (int j = 0; j < 16; ++j) po[j] = 0.f;
        const float4* tb = (const float4*)&sBuf[px * 132];
        #pragma unroll 4
        for (int k4 = 0; k4 < 32; ++k4) {
            float4 tv = tb[k4];
            const float* w0 = wpT + (k4 * 4 + 0) * 64 + og;
            const float* w1 = wpT + (k4 * 4 + 1) * 64 + og;
            const float* w2 = wpT + (k4 * 4 + 2) * 64 + og;
            const float* w3 = wpT + (k4 * 4 + 3) * 64 + og;
            #pragma unroll
            for (int j = 0; j < 16; ++j)
                po[j] = fmaf(w0[j], tv.x,
                        fmaf(w1[j], tv.y,
                        fmaf(w2[j], tv.z,
                        fmaf(w3[j], tv.w, po[j]))));
        }
        int grow = r0 + (p >> 5) * 8 + (px >> 3);
        int gcol = (p & 31) * 8 + (px & 7);
        float* ob = outp + ((size_t)(b * 64 + og)) * HW + grow * 256 + gcol;
        #pragma unroll
        for (int j = 0; j < 16; ++j) ob[(size_t)j * HW] = po[j];
    }
}

extern "C" void kernel_launch(void* const* d_in, const int* in_sizes, int n_in,
                              void* d_out, int out_size, void* d_ws, size_t ws_size,
                              hipStream_t stream) {
    const float* x     = (const float*)d_in[0];
    const float* prior = (const float*)d_in[1];
    const float* wk    = (const float*)d_in[2];
    const float* wh    = (const float*)d_in[3];
    const float* wdw   = (const float*)d_in[4];
    const float* wp    = (const float*)d_in[5];
    const float* lnw   = (const float*)d_in[6];
    const float* lnb   = (const float*)d_in[7];
    float* out = (float*)d_out;
    float* ws  = (float*)d_ws;

    float* kv  = ws;
    float* whT = ws + 512;
    float* wpT = ws + 512 + 24576;
    unsigned short* hid = (unsigned short*)(ws + 40960);        // [4][384][66][256] bf16
    unsigned short* qkv = hid + (size_t)4 * 384 * HSZ2;         // [4][384][256][64] bf16

    k_prep<<<dim3(130), dim3(256), 0, stream>>>(prior, wk, wh, wp, kv, whT, wpT);
    for (int slab = 0; slab < 4; ++slab) {
        int r0 = slab * SLAB;
        k2_hidden<<<dim3(HROWS, 4, 8), dim3(256), 0, stream>>>(x, whT, kv, hid, r0);
        k3_dw<<<dim3(8, 192, 4), dim3(256), 0, stream>>>(hid, wdw, qkv);
        kC_patch<<<dim3(256, 4), dim3(256), 0, stream>>>(qkv, wpT, lnw, lnb, out, r0);
    }
}